// Round 1
// baseline (16574.139 us; speedup 1.0000x reference)
//
#include <hip/hip_runtime.h>
#include <hip/hip_bf16.h>

namespace {

constexpr int Bb = 8;
constexpr int Lr = 512;
constexpr int Dd = 1024;
constexpr int Mm = 64;
constexpr int Tt = 8;
constexpr int NR = 2 * Mm + 1;   // 129
constexpr int BL = Bb * Lr;      // 4096

constexpr int BM = 64, BN = 64, BK = 16;

// C[m,n] = alpha * (sum_k A[m,k] * W[n,k] + bias[n])   (A: [M x K] lda, W: [N x K] ldw)
__global__ __launch_bounds__(256)
void gemm_awt_k(const float* __restrict__ A, int lda,
                const float* __restrict__ W, int ldw,
                const float* __restrict__ bias,
                float* __restrict__ C, int ldc,
                int Nx, int Kx, float alpha)
{
    __shared__ float As[BM][BK + 1];
    __shared__ float Ws[BN][BK + 1];
    const int tx = threadIdx.x, ty = threadIdx.y;
    const int tid = ty * 16 + tx;
    const int m0 = blockIdx.y * BM;
    const int n0 = blockIdx.x * BN;
    const int la = tid >> 2;
    const int k4 = (tid & 3) << 2;
    float acc[4][4] = {};
    for (int k0 = 0; k0 < Kx; k0 += BK) {
        float4 av = *(const float4*)(A + (size_t)(m0 + la) * lda + k0 + k4);
        As[la][k4 + 0] = av.x; As[la][k4 + 1] = av.y;
        As[la][k4 + 2] = av.z; As[la][k4 + 3] = av.w;
        float4 wv = make_float4(0.f, 0.f, 0.f, 0.f);
        if (n0 + la < Nx)
            wv = *(const float4*)(W + (size_t)(n0 + la) * ldw + k0 + k4);
        Ws[la][k4 + 0] = wv.x; Ws[la][k4 + 1] = wv.y;
        Ws[la][k4 + 2] = wv.z; Ws[la][k4 + 3] = wv.w;
        __syncthreads();
        #pragma unroll
        for (int kk = 0; kk < BK; ++kk) {
            float a[4], w[4];
            #pragma unroll
            for (int i = 0; i < 4; ++i) a[i] = As[ty * 4 + i][kk];
            #pragma unroll
            for (int j = 0; j < 4; ++j) w[j] = Ws[tx * 4 + j][kk];
            #pragma unroll
            for (int i = 0; i < 4; ++i)
                #pragma unroll
                for (int j = 0; j < 4; ++j)
                    acc[i][j] = fmaf(a[i], w[j], acc[i][j]);
        }
        __syncthreads();
    }
    #pragma unroll
    for (int i = 0; i < 4; ++i) {
        const int m = m0 + ty * 4 + i;
        #pragma unroll
        for (int j = 0; j < 4; ++j) {
            const int n = n0 + tx * 4 + j;
            if (n < Nx) {
                float v = acc[i][j] + (bias ? bias[n] : 0.f);
                C[(size_t)m * ldc + n] = alpha * v;
            }
        }
    }
}

// Batched: sc[b,i,j] = q[b,i,:].k[b,j,:] + qrel[b,i, clip(j-i)+M]
__global__ __launch_bounds__(256)
void gemm_scores_k(const float* __restrict__ q, const float* __restrict__ kmat,
                   const float* __restrict__ qrel, float* __restrict__ sc)
{
    __shared__ float As[BM][BK + 1];
    __shared__ float Ws[BN][BK + 1];
    const int b = blockIdx.z;
    const float* A = q    + (size_t)b * Lr * Dd;
    const float* W = kmat + (size_t)b * Lr * Dd;
    const int tx = threadIdx.x, ty = threadIdx.y;
    const int tid = ty * 16 + tx;
    const int m0 = blockIdx.y * BM;
    const int n0 = blockIdx.x * BN;
    const int la = tid >> 2;
    const int k4 = (tid & 3) << 2;
    float acc[4][4] = {};
    for (int k0 = 0; k0 < Dd; k0 += BK) {
        float4 av = *(const float4*)(A + (size_t)(m0 + la) * Dd + k0 + k4);
        As[la][k4 + 0] = av.x; As[la][k4 + 1] = av.y;
        As[la][k4 + 2] = av.z; As[la][k4 + 3] = av.w;
        float4 wv = *(const float4*)(W + (size_t)(n0 + la) * Dd + k0 + k4);
        Ws[la][k4 + 0] = wv.x; Ws[la][k4 + 1] = wv.y;
        Ws[la][k4 + 2] = wv.z; Ws[la][k4 + 3] = wv.w;
        __syncthreads();
        #pragma unroll
        for (int kk = 0; kk < BK; ++kk) {
            float a[4], w[4];
            #pragma unroll
            for (int i = 0; i < 4; ++i) a[i] = As[ty * 4 + i][kk];
            #pragma unroll
            for (int j = 0; j < 4; ++j) w[j] = Ws[tx * 4 + j][kk];
            #pragma unroll
            for (int i = 0; i < 4; ++i)
                #pragma unroll
                for (int j = 0; j < 4; ++j)
                    acc[i][j] = fmaf(a[i], w[j], acc[i][j]);
        }
        __syncthreads();
    }
    #pragma unroll
    for (int i = 0; i < 4; ++i) {
        const int ig = m0 + ty * 4 + i;
        #pragma unroll
        for (int j = 0; j < 4; ++j) {
            const int jg = n0 + tx * 4 + j;
            int d = jg - ig;
            d = d < -Mm ? -Mm : (d > Mm ? Mm : d);
            float v = acc[i][j] + qrel[((size_t)b * Lr + ig) * NR + d + Mm];
            sc[((size_t)b * Lr + ig) * Lr + jg] = v;
        }
    }
}

// Masked softmax over j; writes probs into out[b,i,t,j] layout
__global__ __launch_bounds__(256)
void softmax_k(const float* __restrict__ sc, const int* __restrict__ spw,
               float* __restrict__ outp, int t)
{
    const int b = blockIdx.y, i = blockIdx.x;
    const float* srow = sc + ((size_t)b * Lr + i) * Lr;
    const int tidx = threadIdx.x;
    float s0, s1;
    {
        int w = spw[b * Lr + tidx];
        s0 = (w != 0 && t <= w) ? srow[tidx] : -1e18f;
        w = spw[b * Lr + tidx + 256];
        s1 = (w != 0 && t <= w) ? srow[tidx + 256] : -1e18f;
    }
    float mx = fmaxf(s0, s1);
    #pragma unroll
    for (int off = 32; off > 0; off >>= 1) mx = fmaxf(mx, __shfl_down(mx, off));
    __shared__ float redm[4], reds[4];
    const int lane = tidx & 63, wid = tidx >> 6;
    if (lane == 0) redm[wid] = mx;
    __syncthreads();
    mx = fmaxf(fmaxf(redm[0], redm[1]), fmaxf(redm[2], redm[3]));
    const float e0 = expf(s0 - mx), e1 = expf(s1 - mx);
    float sum = e0 + e1;
    #pragma unroll
    for (int off = 32; off > 0; off >>= 1) sum += __shfl_down(sum, off);
    if (lane == 0) reds[wid] = sum;
    __syncthreads();
    const float tot = reds[0] + reds[1] + reds[2] + reds[3];
    float* orow = outp + (((size_t)b * Lr + i) * Tt + t) * Lr;
    orow[tidx]       = e0 / tot;
    orow[tidx + 256] = e1 / tot;
}

// Batched: C[b,i,d] = sum_j P[b,i,j] * V[b,j,d]; P rows strided by Tt*Lr
__global__ __launch_bounds__(256)
void gemm_pv_k(const float* __restrict__ P, const float* __restrict__ V,
               float* __restrict__ C)
{
    __shared__ float As[BM][BK + 1];
    __shared__ float Bs[BK][BN + 1];
    const int b = blockIdx.z;
    const float* A  = P + (size_t)b * Lr * Tt * Lr;   // row stride Tt*Lr
    const float* Bv = V + (size_t)b * Lr * Dd;
    float* Cb       = C + (size_t)b * Lr * Dd;
    const int tx = threadIdx.x, ty = threadIdx.y;
    const int tid = ty * 16 + tx;
    const int m0 = blockIdx.y * BM;
    const int n0 = blockIdx.x * BN;
    const int la = tid >> 2;
    const int k4 = (tid & 3) << 2;
    const int kr = tid >> 4;
    const int n4 = (tid & 15) << 2;
    float acc[4][4] = {};
    for (int k0 = 0; k0 < Lr; k0 += BK) {
        float4 av = *(const float4*)(A + (size_t)(m0 + la) * (Tt * Lr) + k0 + k4);
        As[la][k4 + 0] = av.x; As[la][k4 + 1] = av.y;
        As[la][k4 + 2] = av.z; As[la][k4 + 3] = av.w;
        float4 bv = *(const float4*)(Bv + (size_t)(k0 + kr) * Dd + n0 + n4);
        Bs[kr][n4 + 0] = bv.x; Bs[kr][n4 + 1] = bv.y;
        Bs[kr][n4 + 2] = bv.z; Bs[kr][n4 + 3] = bv.w;
        __syncthreads();
        #pragma unroll
        for (int kk = 0; kk < BK; ++kk) {
            float a[4], w[4];
            #pragma unroll
            for (int i = 0; i < 4; ++i) a[i] = As[ty * 4 + i][kk];
            #pragma unroll
            for (int j = 0; j < 4; ++j) w[j] = Bs[kk][tx * 4 + j];
            #pragma unroll
            for (int i = 0; i < 4; ++i)
                #pragma unroll
                for (int j = 0; j < 4; ++j)
                    acc[i][j] = fmaf(a[i], w[j], acc[i][j]);
        }
        __syncthreads();
    }
    #pragma unroll
    for (int i = 0; i < 4; ++i)
        #pragma unroll
        for (int j = 0; j < 4; ++j)
            Cb[(size_t)(m0 + ty * 4 + i) * Dd + n0 + tx * 4 + j] = acc[i][j];
}

// out[m,d] = relu( sum_e h[m,e]*Wc[d,e] + sum_e hc[m,e]*Wc[d,Dd+e] + cb[d] )
__global__ __launch_bounds__(256)
void gemm_comb_k(const float* __restrict__ h, const float* __restrict__ hc,
                 const float* __restrict__ Wc, const float* __restrict__ cb,
                 float* __restrict__ outh)
{
    __shared__ float As[BM][BK + 1];
    __shared__ float Ws[BN][BK + 1];
    const int tx = threadIdx.x, ty = threadIdx.y;
    const int tid = ty * 16 + tx;
    const int m0 = blockIdx.y * BM;
    const int n0 = blockIdx.x * BN;
    const int la = tid >> 2;
    const int k4 = (tid & 3) << 2;
    float acc[4][4] = {};
    for (int k0 = 0; k0 < 2 * Dd; k0 += BK) {
        const int kg = k0 + k4;
        const float* src = (kg < Dd) ? (h  + (size_t)(m0 + la) * Dd + kg)
                                     : (hc + (size_t)(m0 + la) * Dd + kg - Dd);
        float4 av = *(const float4*)src;
        As[la][k4 + 0] = av.x; As[la][k4 + 1] = av.y;
        As[la][k4 + 2] = av.z; As[la][k4 + 3] = av.w;
        float4 wv = *(const float4*)(Wc + (size_t)(n0 + la) * (2 * Dd) + k0 + k4);
        Ws[la][k4 + 0] = wv.x; Ws[la][k4 + 1] = wv.y;
        Ws[la][k4 + 2] = wv.z; Ws[la][k4 + 3] = wv.w;
        __syncthreads();
        #pragma unroll
        for (int kk = 0; kk < BK; ++kk) {
            float a[4], w[4];
            #pragma unroll
            for (int i = 0; i < 4; ++i) a[i] = As[ty * 4 + i][kk];
            #pragma unroll
            for (int j = 0; j < 4; ++j) w[j] = Ws[tx * 4 + j][kk];
            #pragma unroll
            for (int i = 0; i < 4; ++i)
                #pragma unroll
                for (int j = 0; j < 4; ++j)
                    acc[i][j] = fmaf(a[i], w[j], acc[i][j]);
        }
        __syncthreads();
    }
    #pragma unroll
    for (int i = 0; i < 4; ++i) {
        const int m = m0 + ty * 4 + i;
        #pragma unroll
        for (int j = 0; j < 4; ++j) {
            const int n = n0 + tx * 4 + j;
            float v = acc[i][j] + cb[n];
            outh[(size_t)m * Dd + n] = fmaxf(v, 0.f);
        }
    }
}

__global__ void masks_k(const int* __restrict__ spw, float* __restrict__ out2)
{
    const int idx = blockIdx.x * 256 + threadIdx.x;
    if (idx < BL) {
        const int w = spw[idx];
        #pragma unroll
        for (int t = 0; t < Tt; ++t)
            out2[(size_t)idx * Tt + t] = (w != 0 && t <= w) ? 1.f : 0.f;
    }
}

} // namespace

extern "C" void kernel_launch(void* const* d_in, const int* in_sizes, int n_in,
                              void* d_out, int out_size, void* d_ws, size_t ws_size,
                              hipStream_t stream)
{
    const float* hid  = (const float*)d_in[0];
    const int*   spw  = (const int*)d_in[1];
    const float* Wq[2] = {(const float*)d_in[2], (const float*)d_in[7]};
    const float* bq[2] = {(const float*)d_in[3], (const float*)d_in[8]};
    const float* Wk[2] = {(const float*)d_in[4], (const float*)d_in[9]};
    const float* bk[2] = {(const float*)d_in[5], (const float*)d_in[10]};
    const float* rel[2]= {(const float*)d_in[6], (const float*)d_in[11]};
    const float* combW = (const float*)d_in[12];
    const float* combB = (const float*)d_in[13];

    float* out0 = (float*)d_out;
    float* out1 = out0 + (size_t)BL * Tt * Lr;
    float* out2 = out1 + (size_t)BL * Tt * Lr;
    float* outs[2] = {out0, out1};

    float* ws = (float*)d_ws;
    const size_t BLD = (size_t)BL * Dd;
    float* hbuf[2][2];
    hbuf[0][0] = ws;           hbuf[0][1] = ws + BLD;
    hbuf[1][0] = ws + 2 * BLD; hbuf[1][1] = ws + 3 * BLD;
    float* qb    = ws + 4 * BLD;   // reused as hidc after softmax
    float* kbuf  = ws + 5 * BLD;
    float* qrelb = ws + 6 * BLD;
    float* scb   = qrelb + (size_t)BL * NR;

    hipMemcpyAsync(hbuf[0][0], hid, BLD * sizeof(float), hipMemcpyDeviceToDevice, stream);
    hipMemcpyAsync(hbuf[1][0], hid, BLD * sizeof(float), hipMemcpyDeviceToDevice, stream);
    masks_k<<<dim3((BL + 255) / 256), dim3(256), 0, stream>>>(spw, out2);

    const dim3 thr(16, 16);
    const float inv_sqrt_d = 0.03125f;   // 1/sqrt(1024)
    int cur[2] = {0, 0};

    for (int t = 0; t < Tt; ++t) {
        for (int s = 0; s < 2; ++s) {
            float* hcur = hbuf[s][cur[s]];
            float* hnxt = hbuf[s][cur[s] ^ 1];
            // q = (h @ Wq^T + bq) / sqrt(D)
            gemm_awt_k<<<dim3(Dd / BN, BL / BM), thr, 0, stream>>>(
                hcur, Dd, Wq[s], Dd, bq[s], qb, Dd, Dd, Dd, inv_sqrt_d);
            // k = h @ Wk^T + bk
            gemm_awt_k<<<dim3(Dd / BN, BL / BM), thr, 0, stream>>>(
                hcur, Dd, Wk[s], Dd, bk[s], kbuf, Dd, Dd, Dd, 1.0f);
            // qrel = q @ rel^T
            gemm_awt_k<<<dim3((NR + BN - 1) / BN, BL / BM), thr, 0, stream>>>(
                qb, Dd, rel[s], Dd, nullptr, qrelb, NR, NR, Dd, 1.0f);
            // scores = q k^T + rel-epilogue
            gemm_scores_k<<<dim3(Lr / BN, Lr / BM, Bb), thr, 0, stream>>>(
                qb, kbuf, qrelb, scb);
            // masked softmax -> probs into d_out
            softmax_k<<<dim3(Lr, Bb), dim3(256), 0, stream>>>(scb, spw, outs[s], t);
            // hidc = probs @ h (probs read from d_out, strided); write into qb
            gemm_pv_k<<<dim3(Dd / BN, Lr / BM, Bb), thr, 0, stream>>>(
                outs[s] + (size_t)t * Lr, hcur, qb);
            // h' = relu(concat(h, hidc) @ combW^T + combB)
            gemm_comb_k<<<dim3(Dd / BN, BL / BM), thr, 0, stream>>>(
                hcur, qb, combW, combB, hnxt);
            cur[s] ^= 1;
        }
    }
}

// Round 2
// 2843.957 us; speedup vs baseline: 5.8278x; 5.8278x over previous
//
#include <hip/hip_runtime.h>
#include <hip/hip_bf16.h>

namespace {

constexpr int Bb = 8;
constexpr int Lr = 512;
constexpr int Dd = 1024;
constexpr int Mm = 64;
constexpr int Tt = 8;
constexpr int BL = Bb * Lr;      // 4096
constexpr int NRP = 132;         // padded row stride for qrel (129 used)

typedef __attribute__((ext_vector_type(8))) short bf16x8;
typedef __attribute__((ext_vector_type(4))) float f32x4;

__device__ __forceinline__ short f2bf(float x) {
    __hip_bfloat16 h = __float2bfloat16(x);
    return *reinterpret_cast<short*>(&h);
}

// ---------------------------------------------------------------------------
// Core: C_tile(128x128) += A[Mx K] @ B^T, A/B bf16 row-major [rows x K].
// A comes from two pointers: rows use A1 for k<ksplit else A2 (k-ksplit).
// m97 structure: BK=64, global_load_lds w16, 2 barriers/K-step, 4 waves.
// Caller pre-offsets A1/A2 by m0*lda and Bm by n0*ldb.
// ---------------------------------------------------------------------------
__device__ __forceinline__ void gemm_core(
    const short* __restrict__ A1, const short* __restrict__ A2, int ksplit,
    int lda, const short* __restrict__ Bm, int ldb, int K,
    short* As, short* Bs, f32x4 acc[4][4])
{
    const int tid  = threadIdx.x;
    const int lane = tid & 63;
    const int w    = tid >> 6;
    const int wm   = w >> 1, wn = w & 1;
    const int lr   = lane >> 3;         // row within 8-row group
    const int lc   = (lane & 7) << 3;   // elem col: 0,8,..,56

    for (int k0 = 0; k0 < K; k0 += 64) {
        const short* Abase = (k0 < ksplit) ? A1 : A2;
        const int kc = (k0 < ksplit) ? k0 : (k0 - ksplit);
        #pragma unroll
        for (int i = 0; i < 4; ++i) {
            const int r0 = (i * 4 + w) * 8;
            const short* gA = Abase + (size_t)(r0 + lr) * lda + kc + lc;
            __builtin_amdgcn_global_load_lds(
                (const __attribute__((address_space(1))) void*)gA,
                (__attribute__((address_space(3))) void*)(As + r0 * 64), 16, 0, 0);
            const short* gB = Bm + (size_t)(r0 + lr) * ldb + k0 + lc;
            __builtin_amdgcn_global_load_lds(
                (const __attribute__((address_space(1))) void*)gB,
                (__attribute__((address_space(3))) void*)(Bs + r0 * 64), 16, 0, 0);
        }
        __syncthreads();   // drains vmcnt(0) before barrier
        #pragma unroll
        for (int ks = 0; ks < 2; ++ks) {
            bf16x8 af[4], bb[4];
            #pragma unroll
            for (int f = 0; f < 4; ++f) {
                af[f] = *(const bf16x8*)(As + (wm * 64 + f * 16 + (lane & 15)) * 64
                                            + ks * 32 + ((lane >> 4) << 3));
                bb[f] = *(const bf16x8*)(Bs + (wn * 64 + f * 16 + (lane & 15)) * 64
                                            + ks * 32 + ((lane >> 4) << 3));
            }
            #pragma unroll
            for (int fm = 0; fm < 4; ++fm)
                #pragma unroll
                for (int fn = 0; fn < 4; ++fn)
                    acc[fm][fn] = __builtin_amdgcn_mfma_f32_16x16x32_bf16(
                        af[fm], bb[fn], acc[fm][fn], 0, 0, 0);
        }
        __syncthreads();
    }
}

// q/k projection: out = bf16( (h @ W^T + bias) * alpha )
__global__ __launch_bounds__(256)
void proj_k(const short* __restrict__ h, const short* __restrict__ W,
            const float* __restrict__ bias, float alpha, short* __restrict__ outb)
{
    __shared__ short As[128 * 64], Bs[128 * 64];
    f32x4 acc[4][4] = {};
    const int m0 = blockIdx.y * 128, n0 = blockIdx.x * 128;
    gemm_core(h + (size_t)m0 * Dd, h + (size_t)m0 * Dd, 1 << 30, Dd,
              W + (size_t)n0 * Dd, Dd, Dd, As, Bs, acc);
    const int lane = threadIdx.x & 63, w = threadIdx.x >> 6;
    const int wm = w >> 1, wn = w & 1;
    #pragma unroll
    for (int fm = 0; fm < 4; ++fm)
        #pragma unroll
        for (int fn = 0; fn < 4; ++fn) {
            const int nl = wn * 64 + fn * 16 + (lane & 15);
            #pragma unroll
            for (int r = 0; r < 4; ++r) {
                const int ml = wm * 64 + fm * 16 + ((lane >> 4) << 2) + r;
                outb[(size_t)(m0 + ml) * Dd + n0 + nl] =
                    f2bf((acc[fm][fn][r] + bias[n0 + nl]) * alpha);
            }
        }
}

// qrel = q @ rel^T (rel padded to 256 rows); store fp32 where n<129
__global__ __launch_bounds__(256)
void qrel_k(const short* __restrict__ q, const short* __restrict__ relp,
            float* __restrict__ qrelb)
{
    __shared__ short As[128 * 64], Bs[128 * 64];
    f32x4 acc[4][4] = {};
    const int m0 = blockIdx.y * 128, n0 = blockIdx.x * 128;
    gemm_core(q + (size_t)m0 * Dd, q + (size_t)m0 * Dd, 1 << 30, Dd,
              relp + (size_t)n0 * Dd, Dd, Dd, As, Bs, acc);
    const int lane = threadIdx.x & 63, w = threadIdx.x >> 6;
    const int wm = w >> 1, wn = w & 1;
    #pragma unroll
    for (int fm = 0; fm < 4; ++fm)
        #pragma unroll
        for (int fn = 0; fn < 4; ++fn) {
            const int nl = wn * 64 + fn * 16 + (lane & 15);
            if (n0 + nl < 129) {
                #pragma unroll
                for (int r = 0; r < 4; ++r) {
                    const int ml = wm * 64 + fm * 16 + ((lane >> 4) << 2) + r;
                    qrelb[(size_t)(m0 + ml) * NRP + n0 + nl] = acc[fm][fn][r];
                }
            }
        }
}

// scores[b,i,j] = q_b[i,:].k_b[j,:] + qrel[b*L+i, clip(j-i)+M]  (fp32 out)
__global__ __launch_bounds__(256)
void scores_k(const short* __restrict__ q, const short* __restrict__ kmat,
              const float* __restrict__ qrelb, float* __restrict__ scb)
{
    __shared__ short As[128 * 64], Bs[128 * 64];
    f32x4 acc[4][4] = {};
    const int b = blockIdx.z;
    const int m0 = blockIdx.y * 128, n0 = blockIdx.x * 128;
    const short* A = q    + ((size_t)b * Lr + m0) * Dd;
    const short* B = kmat + ((size_t)b * Lr + n0) * Dd;
    gemm_core(A, A, 1 << 30, Dd, B, Dd, Dd, As, Bs, acc);
    const int lane = threadIdx.x & 63, w = threadIdx.x >> 6;
    const int wm = w >> 1, wn = w & 1;
    #pragma unroll
    for (int fm = 0; fm < 4; ++fm)
        #pragma unroll
        for (int fn = 0; fn < 4; ++fn) {
            const int j = n0 + wn * 64 + fn * 16 + (lane & 15);
            #pragma unroll
            for (int r = 0; r < 4; ++r) {
                const int i = m0 + wm * 64 + fm * 16 + ((lane >> 4) << 2) + r;
                int d = j - i;
                d = d < -Mm ? -Mm : (d > Mm ? Mm : d);
                scb[((size_t)b * Lr + i) * Lr + j] =
                    acc[fm][fn][r] + qrelb[((size_t)b * Lr + i) * NRP + d + Mm];
            }
        }
}

// hc[b*L+i, n] = sum_j P[b,i,j] * hidT[b, n, j]   (PV via transposed V)
__global__ __launch_bounds__(256)
void pv_k(const short* __restrict__ probs, const short* __restrict__ hidT,
          short* __restrict__ hc)
{
    __shared__ short As[128 * 64], Bs[128 * 64];
    f32x4 acc[4][4] = {};
    const int b = blockIdx.z;
    const int m0 = blockIdx.y * 128, n0 = blockIdx.x * 128;
    const short* A = probs + ((size_t)b * Lr + m0) * Lr;
    const short* B = hidT  + ((size_t)b * Dd + n0) * Lr;
    gemm_core(A, A, 1 << 30, Lr, B, Lr, Lr, As, Bs, acc);
    const int lane = threadIdx.x & 63, w = threadIdx.x >> 6;
    const int wm = w >> 1, wn = w & 1;
    #pragma unroll
    for (int fm = 0; fm < 4; ++fm)
        #pragma unroll
        for (int fn = 0; fn < 4; ++fn) {
            const int n = n0 + wn * 64 + fn * 16 + (lane & 15);
            #pragma unroll
            for (int r = 0; r < 4; ++r) {
                const int i = m0 + wm * 64 + fm * 16 + ((lane >> 4) << 2) + r;
                hc[((size_t)b * Lr + i) * Dd + n] = f2bf(acc[fm][fn][r]);
            }
        }
}

// h' = relu(concat(h,hc) @ Wc^T + cb); writes bf16 h' and transposed hidT
__global__ __launch_bounds__(256)
void comb_k(const short* __restrict__ h, const short* __restrict__ hc,
            const short* __restrict__ Wc, const float* __restrict__ cb,
            short* __restrict__ hout, short* __restrict__ hidT)
{
    __shared__ short As[128 * 64], Bs[128 * 64];
    f32x4 acc[4][4] = {};
    const int m0 = blockIdx.y * 128, n0 = blockIdx.x * 128;
    gemm_core(h + (size_t)m0 * Dd, hc + (size_t)m0 * Dd, Dd, Dd,
              Wc + (size_t)n0 * 2 * Dd, 2 * Dd, 2 * Dd, As, Bs, acc);
    const int lane = threadIdx.x & 63, w = threadIdx.x >> 6;
    const int wm = w >> 1, wn = w & 1;
    const int b = m0 >> 9;            // 128 | 512 → whole tile in one batch
    const int il_base = (m0 & 511) + wm * 64 + ((lane >> 4) << 2);
    #pragma unroll
    for (int fm = 0; fm < 4; ++fm)
        #pragma unroll
        for (int fn = 0; fn < 4; ++fn) {
            const int n = n0 + wn * 64 + fn * 16 + (lane & 15);
            const float bias = cb[n];
            short4 pk;
            short* pks = reinterpret_cast<short*>(&pk);
            #pragma unroll
            for (int r = 0; r < 4; ++r) {
                const int m = m0 + wm * 64 + fm * 16 + ((lane >> 4) << 2) + r;
                const float v = fmaxf(acc[fm][fn][r] + bias, 0.f);
                const short s = f2bf(v);
                hout[(size_t)m * Dd + n] = s;
                pks[r] = s;
            }
            *reinterpret_cast<short4*>(
                &hidT[((size_t)b * Dd + n) * Lr + il_base + fm * 16]) = pk;
        }
}

// Masked softmax over j; fp32 probs into d_out[b,i,t,j], bf16 copy to ws
__global__ __launch_bounds__(256)
void softmax_k(const float* __restrict__ sc, const int* __restrict__ spw,
               float* __restrict__ outp, short* __restrict__ probs, int t)
{
    const int b = blockIdx.y, i = blockIdx.x;
    const float* srow = sc + ((size_t)b * Lr + i) * Lr;
    const int tidx = threadIdx.x;
    float s0, s1;
    {
        int w = spw[b * Lr + tidx];
        s0 = (w != 0 && t <= w) ? srow[tidx] : -1e18f;
        w = spw[b * Lr + tidx + 256];
        s1 = (w != 0 && t <= w) ? srow[tidx + 256] : -1e18f;
    }
    float mx = fmaxf(s0, s1);
    #pragma unroll
    for (int off = 32; off > 0; off >>= 1) mx = fmaxf(mx, __shfl_down(mx, off));
    __shared__ float redm[4], reds[4];
    const int lane = tidx & 63, wid = tidx >> 6;
    if (lane == 0) redm[wid] = mx;
    __syncthreads();
    mx = fmaxf(fmaxf(redm[0], redm[1]), fmaxf(redm[2], redm[3]));
    const float e0 = expf(s0 - mx), e1 = expf(s1 - mx);
    float sum = e0 + e1;
    #pragma unroll
    for (int off = 32; off > 0; off >>= 1) sum += __shfl_down(sum, off);
    if (lane == 0) reds[wid] = sum;
    __syncthreads();
    const float inv = 1.f / (reds[0] + reds[1] + reds[2] + reds[3]);
    const float p0 = e0 * inv, p1 = e1 * inv;
    float* orow = outp + (((size_t)b * Lr + i) * Tt + t) * Lr;
    orow[tidx]       = p0;
    orow[tidx + 256] = p1;
    short* prow = probs + ((size_t)b * Lr + i) * Lr;
    prow[tidx]       = f2bf(p0);
    prow[tidx + 256] = f2bf(p1);
}

__global__ void masks_k(const int* __restrict__ spw, float* __restrict__ out2)
{
    const int idx = blockIdx.x * 256 + threadIdx.x;
    if (idx < BL) {
        const int w = spw[idx];
        #pragma unroll
        for (int t = 0; t < Tt; ++t)
            out2[(size_t)idx * Tt + t] = (w != 0 && t <= w) ? 1.f : 0.f;
    }
}

__global__ void f2bf_k(const float* __restrict__ src, short* __restrict__ dst, int n)
{
    const int idx = blockIdx.x * 256 + threadIdx.x;
    if (idx < n) dst[idx] = f2bf(src[idx]);
}

__global__ void relpad_k(const float* __restrict__ rel, short* __restrict__ dst)
{
    const int idx = blockIdx.x * 256 + threadIdx.x;   // 256*1024 total
    if (idx < 256 * 1024) {
        const int row = idx >> 10;
        dst[idx] = (row < 129) ? f2bf(rel[idx]) : (short)0;
    }
}

__global__ void hidinit_k(const float* __restrict__ hid,
                          short* __restrict__ h_st, short* __restrict__ h_ed,
                          short* __restrict__ hT_st, short* __restrict__ hT_ed)
{
    const int idx = blockIdx.x * 256 + threadIdx.x;   // 4096*1024 total
    if (idx < BL * Dd) {
        const int i = idx >> 10, d = idx & 1023;
        const int b = i >> 9, il = i & 511;
        const short s = f2bf(hid[idx]);
        h_st[idx] = s;
        h_ed[idx] = s;
        hT_st[((size_t)b * Dd + d) * Lr + il] = s;
        hT_ed[((size_t)b * Dd + d) * Lr + il] = s;
    }
}

} // namespace

extern "C" void kernel_launch(void* const* d_in, const int* in_sizes, int n_in,
                              void* d_out, int out_size, void* d_ws, size_t ws_size,
                              hipStream_t stream)
{
    const float* hid  = (const float*)d_in[0];
    const int*   spw  = (const int*)d_in[1];
    const float* Wq[2] = {(const float*)d_in[2], (const float*)d_in[7]};
    const float* bq[2] = {(const float*)d_in[3], (const float*)d_in[8]};
    const float* Wk[2] = {(const float*)d_in[4], (const float*)d_in[9]};
    const float* bk[2] = {(const float*)d_in[5], (const float*)d_in[10]};
    const float* rel[2]= {(const float*)d_in[6], (const float*)d_in[11]};
    const float* combW = (const float*)d_in[12];
    const float* combB = (const float*)d_in[13];

    float* out0 = (float*)d_out;
    float* out1 = out0 + (size_t)BL * Tt * Lr;
    float* out2 = out1 + (size_t)BL * Tt * Lr;
    float* outs[2] = {out0, out1};

    // ---- workspace layout (shorts then floats) ----
    short* wsS = (short*)d_ws;
    const size_t H = (size_t)BL * Dd;           // 4,194,304
    size_t cur = 0;
    short* hbuf[2][2];
    hbuf[0][0] = wsS + cur; cur += H;
    hbuf[0][1] = wsS + cur; cur += H;
    hbuf[1][0] = wsS + cur; cur += H;
    hbuf[1][1] = wsS + cur; cur += H;
    short* hidT[2];
    hidT[0] = wsS + cur; cur += H;
    hidT[1] = wsS + cur; cur += H;
    short* hc  = wsS + cur; cur += H;
    short* qb  = wsS + cur; cur += H;
    short* kb  = wsS + cur; cur += H;
    short* probs = wsS + cur; cur += (size_t)Bb * Lr * Lr;          // 2M
    short* wqb[2], *wkb[2];
    wqb[0] = wsS + cur; cur += (size_t)Dd * Dd;
    wkb[0] = wsS + cur; cur += (size_t)Dd * Dd;
    wqb[1] = wsS + cur; cur += (size_t)Dd * Dd;
    wkb[1] = wsS + cur; cur += (size_t)Dd * Dd;
    short* combWb = wsS + cur; cur += (size_t)Dd * 2 * Dd;
    short* relp[2];
    relp[0] = wsS + cur; cur += (size_t)256 * Dd;
    relp[1] = wsS + cur; cur += (size_t)256 * Dd;
    float* wsF = (float*)(wsS + cur);
    float* qrelb = wsF;                                  // 4096*132 fp32
    float* scb   = wsF + (size_t)BL * NRP;               // 8*512*512 fp32

    // ---- setup: conversions (every launch; graph-safe) ----
    const int DD = Dd * Dd;
    f2bf_k<<<dim3((DD + 255) / 256), 256, 0, stream>>>(Wq[0], wqb[0], DD);
    f2bf_k<<<dim3((DD + 255) / 256), 256, 0, stream>>>(Wk[0], wkb[0], DD);
    f2bf_k<<<dim3((DD + 255) / 256), 256, 0, stream>>>(Wq[1], wqb[1], DD);
    f2bf_k<<<dim3((DD + 255) / 256), 256, 0, stream>>>(Wk[1], wkb[1], DD);
    f2bf_k<<<dim3((2 * DD + 255) / 256), 256, 0, stream>>>(combW, combWb, 2 * DD);
    relpad_k<<<dim3(256 * Dd / 256), 256, 0, stream>>>(rel[0], relp[0]);
    relpad_k<<<dim3(256 * Dd / 256), 256, 0, stream>>>(rel[1], relp[1]);
    hidinit_k<<<dim3((int)(H / 256)), 256, 0, stream>>>(hid, hbuf[0][0], hbuf[1][0],
                                                        hidT[0], hidT[1]);
    masks_k<<<dim3((BL + 255) / 256), 256, 0, stream>>>(spw, out2);

    const float inv_sqrt_d = 0.03125f;   // 1/sqrt(1024)
    int curb[2] = {0, 0};

    for (int t = 0; t < Tt; ++t) {
        for (int s = 0; s < 2; ++s) {
            short* hcur = hbuf[s][curb[s]];
            short* hnxt = hbuf[s][curb[s] ^ 1];
            proj_k<<<dim3(8, 32), 256, 0, stream>>>(hcur, wqb[s], bq[s], inv_sqrt_d, qb);
            proj_k<<<dim3(8, 32), 256, 0, stream>>>(hcur, wkb[s], bk[s], 1.0f, kb);
            qrel_k<<<dim3(2, 32), 256, 0, stream>>>(qb, relp[s], qrelb);
            scores_k<<<dim3(4, 4, Bb), 256, 0, stream>>>(qb, kb, qrelb, scb);
            softmax_k<<<dim3(Lr, Bb), 256, 0, stream>>>(scb, spw, outs[s], probs, t);
            pv_k<<<dim3(8, 4, Bb), 256, 0, stream>>>(probs, hidT[s], hc);
            comb_k<<<dim3(8, 32), 256, 0, stream>>>(hcur, hc, combWb, combB,
                                                    hnxt, hidT[s]);
            curb[s] ^= 1;
        }
    }
}

// Round 3
// 1705.911 us; speedup vs baseline: 9.7157x; 1.6671x over previous
//
#include <hip/hip_runtime.h>
#include <hip/hip_bf16.h>

namespace {

constexpr int Bb = 8;
constexpr int Lr = 512;
constexpr int Dd = 1024;
constexpr int Mm = 64;
constexpr int Tt = 8;
constexpr int BL = Bb * Lr;      // 4096
constexpr int NRP = 132;         // padded row stride for qrel (129 used)

constexpr size_t H  = (size_t)BL * Dd;        // per-stream hid elems
constexpr size_t QS = (size_t)BL * NRP;       // per-stream qrel elems
constexpr size_t SC = (size_t)Bb * Lr * Lr;   // per-stream scores elems
constexpr size_t PS = SC;                     // per-stream probs elems

typedef __attribute__((ext_vector_type(8))) short bf16x8;
typedef __attribute__((ext_vector_type(4))) float f32x4;

__device__ __forceinline__ short f2bf(float x) {
    __hip_bfloat16 h = __float2bfloat16(x);
    return *reinterpret_cast<short*>(&h);
}

// ---------------------------------------------------------------------------
// Core: C_tile(128x128) += A @ B^T, A/B bf16 row-major [rows x K].
// A rows use A1 for k<ksplit else A2 (k-ksplit). m97 structure: BK=64,
// global_load_lds w16, 2 barriers/K-step, 4 waves (256 thr).
// ---------------------------------------------------------------------------
__device__ __forceinline__ void gemm_core(
    const short* __restrict__ A1, const short* __restrict__ A2, int ksplit,
    int lda, const short* __restrict__ Bm, int ldb, int K,
    short* As, short* Bs, f32x4 acc[4][4])
{
    const int tid  = threadIdx.x;
    const int lane = tid & 63;
    const int w    = tid >> 6;
    const int wm   = w >> 1, wn = w & 1;
    const int lr   = lane >> 3;         // row within 8-row group
    const int lc   = (lane & 7) << 3;   // elem col: 0,8,..,56

    for (int k0 = 0; k0 < K; k0 += 64) {
        const short* Abase = (k0 < ksplit) ? A1 : A2;
        const int kc = (k0 < ksplit) ? k0 : (k0 - ksplit);
        #pragma unroll
        for (int i = 0; i < 4; ++i) {
            const int r0 = (i * 4 + w) * 8;
            const short* gA = Abase + (size_t)(r0 + lr) * lda + kc + lc;
            __builtin_amdgcn_global_load_lds(
                (const __attribute__((address_space(1))) void*)gA,
                (__attribute__((address_space(3))) void*)(As + r0 * 64), 16, 0, 0);
            const short* gB = Bm + (size_t)(r0 + lr) * ldb + k0 + lc;
            __builtin_amdgcn_global_load_lds(
                (const __attribute__((address_space(1))) void*)gB,
                (__attribute__((address_space(3))) void*)(Bs + r0 * 64), 16, 0, 0);
        }
        __syncthreads();
        #pragma unroll
        for (int ks = 0; ks < 2; ++ks) {
            bf16x8 af[4], bb[4];
            #pragma unroll
            for (int f = 0; f < 4; ++f) {
                af[f] = *(const bf16x8*)(As + (wm * 64 + f * 16 + (lane & 15)) * 64
                                            + ks * 32 + ((lane >> 4) << 3));
                bb[f] = *(const bf16x8*)(Bs + (wn * 64 + f * 16 + (lane & 15)) * 64
                                            + ks * 32 + ((lane >> 4) << 3));
            }
            #pragma unroll
            for (int fm = 0; fm < 4; ++fm)
                #pragma unroll
                for (int fn = 0; fn < 4; ++fn)
                    acc[fm][fn] = __builtin_amdgcn_mfma_f32_16x16x32_bf16(
                        af[fm], bb[fn], acc[fm][fn], 0, 0, 0);
        }
        __syncthreads();
    }
}

// Fused q/k projection for BOTH streams: grid (16, 64).
// n-tile < 8 -> q (scaled), else k. m-tile >= 32 -> stream 1.
__global__ __launch_bounds__(256)
void proj2_k(const short* __restrict__ h0, const short* __restrict__ h1,
             const short* __restrict__ wq0, const short* __restrict__ wk0,
             const short* __restrict__ wq1, const short* __restrict__ wk1,
             const float* __restrict__ bq0, const float* __restrict__ bk0,
             const float* __restrict__ bq1, const float* __restrict__ bk1,
             short* __restrict__ qout, short* __restrict__ kout)
{
    __shared__ short As[128 * 64], Bs[128 * 64];
    f32x4 acc[4][4] = {};
    const int m0g = blockIdx.y * 128;
    const int s   = m0g >> 12;
    const int m0  = m0g & 4095;
    const int n0g = blockIdx.x * 128;
    const bool isq = n0g < Dd;
    const int n0  = isq ? n0g : n0g - Dd;
    const short* h    = s ? h1 : h0;
    const short* W    = s ? (isq ? wq1 : wk1) : (isq ? wq0 : wk0);
    const float* bias = s ? (isq ? bq1 : bk1) : (isq ? bq0 : bk0);
    const float alpha = isq ? 0.03125f : 1.0f;
    short* out = (isq ? qout : kout) + (size_t)s * H;
    gemm_core(h + (size_t)m0 * Dd, h + (size_t)m0 * Dd, 1 << 30, Dd,
              W + (size_t)n0 * Dd, Dd, Dd, As, Bs, acc);
    const int lane = threadIdx.x & 63, w = threadIdx.x >> 6;
    const int wm = w >> 1, wn = w & 1;
    #pragma unroll
    for (int fm = 0; fm < 4; ++fm)
        #pragma unroll
        for (int fn = 0; fn < 4; ++fn) {
            const int nl = wn * 64 + fn * 16 + (lane & 15);
            #pragma unroll
            for (int r = 0; r < 4; ++r) {
                const int ml = wm * 64 + fm * 16 + ((lane >> 4) << 2) + r;
                out[(size_t)(m0 + ml) * Dd + n0 + nl] =
                    f2bf((acc[fm][fn][r] + bias[n0 + nl]) * alpha);
            }
        }
}

// qrel = q @ rel^T for both streams: grid (2, 64)
__global__ __launch_bounds__(256)
void qrel2_k(const short* __restrict__ q,
             const short* __restrict__ relp0, const short* __restrict__ relp1,
             float* __restrict__ qrelb)
{
    __shared__ short As[128 * 64], Bs[128 * 64];
    f32x4 acc[4][4] = {};
    const int m0g = blockIdx.y * 128;
    const int s   = m0g >> 12;
    const int m0  = m0g & 4095;
    const int n0  = blockIdx.x * 128;
    const short* A = q + (size_t)s * H + (size_t)m0 * Dd;
    const short* B = (s ? relp1 : relp0) + (size_t)n0 * Dd;
    float* out = qrelb + (size_t)s * QS;
    gemm_core(A, A, 1 << 30, Dd, B, Dd, Dd, As, Bs, acc);
    const int lane = threadIdx.x & 63, w = threadIdx.x >> 6;
    const int wm = w >> 1, wn = w & 1;
    #pragma unroll
    for (int fm = 0; fm < 4; ++fm)
        #pragma unroll
        for (int fn = 0; fn < 4; ++fn) {
            const int nl = wn * 64 + fn * 16 + (lane & 15);
            if (n0 + nl < 129) {
                #pragma unroll
                for (int r = 0; r < 4; ++r) {
                    const int ml = wm * 64 + fm * 16 + ((lane >> 4) << 2) + r;
                    out[(size_t)(m0 + ml) * NRP + n0 + nl] = acc[fm][fn][r];
                }
            }
        }
}

// scores[s,b,i,j] = q.k + qrel gather: grid (4, 4, 16)  z = s*8+b
__global__ __launch_bounds__(256)
void scores2_k(const short* __restrict__ q, const short* __restrict__ kmat,
               const float* __restrict__ qrelb, float* __restrict__ scb)
{
    __shared__ short As[128 * 64], Bs[128 * 64];
    f32x4 acc[4][4] = {};
    const int s = blockIdx.z >> 3, b = blockIdx.z & 7;
    const int m0 = blockIdx.y * 128, n0 = blockIdx.x * 128;
    const short* A = q    + (size_t)s * H + ((size_t)b * Lr + m0) * Dd;
    const short* B = kmat + (size_t)s * H + ((size_t)b * Lr + n0) * Dd;
    const float* qr = qrelb + (size_t)s * QS;
    float* out = scb + (size_t)s * SC;
    gemm_core(A, A, 1 << 30, Dd, B, Dd, Dd, As, Bs, acc);
    const int lane = threadIdx.x & 63, w = threadIdx.x >> 6;
    const int wm = w >> 1, wn = w & 1;
    #pragma unroll
    for (int fm = 0; fm < 4; ++fm)
        #pragma unroll
        for (int fn = 0; fn < 4; ++fn) {
            const int j = n0 + wn * 64 + fn * 16 + (lane & 15);
            #pragma unroll
            for (int r = 0; r < 4; ++r) {
                const int i = m0 + wm * 64 + fm * 16 + ((lane >> 4) << 2) + r;
                int d = j - i;
                d = d < -Mm ? -Mm : (d > Mm ? Mm : d);
                out[((size_t)b * Lr + i) * Lr + j] =
                    acc[fm][fn][r] + qr[((size_t)b * Lr + i) * NRP + d + Mm];
            }
        }
}

// Masked softmax both streams: grid (512, 8, 2)
__global__ __launch_bounds__(256)
void softmax2_k(const float* __restrict__ scb, const int* __restrict__ spw,
                float* __restrict__ out0, float* __restrict__ out1,
                short* __restrict__ probs, int t)
{
    const int i = blockIdx.x, b = blockIdx.y, s = blockIdx.z;
    const float* srow = scb + (size_t)s * SC + ((size_t)b * Lr + i) * Lr;
    const int tidx = threadIdx.x;
    float s0, s1;
    {
        int w = spw[b * Lr + tidx];
        s0 = (w != 0 && t <= w) ? srow[tidx] : -1e18f;
        w = spw[b * Lr + tidx + 256];
        s1 = (w != 0 && t <= w) ? srow[tidx + 256] : -1e18f;
    }
    float mx = fmaxf(s0, s1);
    #pragma unroll
    for (int off = 32; off > 0; off >>= 1) mx = fmaxf(mx, __shfl_down(mx, off));
    __shared__ float redm[4], reds[4];
    const int lane = tidx & 63, wid = tidx >> 6;
    if (lane == 0) redm[wid] = mx;
    __syncthreads();
    mx = fmaxf(fmaxf(redm[0], redm[1]), fmaxf(redm[2], redm[3]));
    const float e0 = expf(s0 - mx), e1 = expf(s1 - mx);
    float sum = e0 + e1;
    #pragma unroll
    for (int off = 32; off > 0; off >>= 1) sum += __shfl_down(sum, off);
    if (lane == 0) reds[wid] = sum;
    __syncthreads();
    const float inv = 1.f / (reds[0] + reds[1] + reds[2] + reds[3]);
    const float p0 = e0 * inv, p1 = e1 * inv;
    float* orow = (s ? out1 : out0) + (((size_t)b * Lr + i) * Tt + t) * Lr;
    orow[tidx]       = p0;
    orow[tidx + 256] = p1;
    short* prow = probs + (size_t)s * PS + ((size_t)b * Lr + i) * Lr;
    prow[tidx]       = f2bf(p0);
    prow[tidx + 256] = f2bf(p1);
}

// hc = P @ hidT^T both streams: grid (8, 4, 16)  z = s*8+b
__global__ __launch_bounds__(256)
void pv2_k(const short* __restrict__ probs,
           const short* __restrict__ hT0, const short* __restrict__ hT1,
           short* __restrict__ hc)
{
    __shared__ short As[128 * 64], Bs[128 * 64];
    f32x4 acc[4][4] = {};
    const int s = blockIdx.z >> 3, b = blockIdx.z & 7;
    const int m0 = blockIdx.y * 128, n0 = blockIdx.x * 128;
    const short* A = probs + (size_t)s * PS + ((size_t)b * Lr + m0) * Lr;
    const short* B = (s ? hT1 : hT0) + ((size_t)b * Dd + n0) * Lr;
    short* out = hc + (size_t)s * H;
    gemm_core(A, A, 1 << 30, Lr, B, Lr, Lr, As, Bs, acc);
    const int lane = threadIdx.x & 63, w = threadIdx.x >> 6;
    const int wm = w >> 1, wn = w & 1;
    #pragma unroll
    for (int fm = 0; fm < 4; ++fm)
        #pragma unroll
        for (int fn = 0; fn < 4; ++fn) {
            const int n = n0 + wn * 64 + fn * 16 + (lane & 15);
            #pragma unroll
            for (int r = 0; r < 4; ++r) {
                const int i = m0 + wm * 64 + fm * 16 + ((lane >> 4) << 2) + r;
                out[((size_t)b * Lr + i) * Dd + n] = f2bf(acc[fm][fn][r]);
            }
        }
}

// h' = relu(concat(h,hc) @ Wc^T + cb), both streams: grid (8, 64)
__global__ __launch_bounds__(256)
void comb2_k(const short* __restrict__ h0, const short* __restrict__ h1,
             const short* __restrict__ hc,
             const short* __restrict__ Wc, const float* __restrict__ cb,
             short* __restrict__ hn0, short* __restrict__ hn1,
             short* __restrict__ hT0, short* __restrict__ hT1)
{
    __shared__ short As[128 * 64], Bs[128 * 64];
    f32x4 acc[4][4] = {};
    const int m0g = blockIdx.y * 128;
    const int s   = m0g >> 12;
    const int m0  = m0g & 4095;
    const int n0  = blockIdx.x * 128;
    const short* h = s ? h1 : h0;
    gemm_core(h + (size_t)m0 * Dd,
              hc + (size_t)s * H + (size_t)m0 * Dd, Dd, Dd,
              Wc + (size_t)n0 * 2 * Dd, 2 * Dd, 2 * Dd, As, Bs, acc);
    short* hout = s ? hn1 : hn0;
    short* hT   = s ? hT1 : hT0;
    const int lane = threadIdx.x & 63, w = threadIdx.x >> 6;
    const int wm = w >> 1, wn = w & 1;
    const int b = m0 >> 9;
    const int il_base = (m0 & 511) + wm * 64 + ((lane >> 4) << 2);
    #pragma unroll
    for (int fm = 0; fm < 4; ++fm)
        #pragma unroll
        for (int fn = 0; fn < 4; ++fn) {
            const int n = n0 + wn * 64 + fn * 16 + (lane & 15);
            const float bias = cb[n];
            short4 pk;
            short* pks = reinterpret_cast<short*>(&pk);
            #pragma unroll
            for (int r = 0; r < 4; ++r) {
                const int m = m0 + wm * 64 + fm * 16 + ((lane >> 4) << 2) + r;
                const float v = fmaxf(acc[fm][fn][r] + bias, 0.f);
                const short sv = f2bf(v);
                hout[(size_t)m * Dd + n] = sv;
                pks[r] = sv;
            }
            *reinterpret_cast<short4*>(
                &hT[((size_t)b * Dd + n) * Lr + il_base + fm * 16]) = pk;
        }
}

__global__ void masks_k(const int* __restrict__ spw, float* __restrict__ out2)
{
    const int idx = blockIdx.x * 256 + threadIdx.x;
    if (idx < BL) {
        const int w = spw[idx];
        #pragma unroll
        for (int t = 0; t < Tt; ++t)
            out2[(size_t)idx * Tt + t] = (w != 0 && t <= w) ? 1.f : 0.f;
    }
}

__global__ void f2bf_k(const float* __restrict__ src, short* __restrict__ dst, int n)
{
    const int idx = blockIdx.x * 256 + threadIdx.x;
    if (idx < n) dst[idx] = f2bf(src[idx]);
}

__global__ void relpad_k(const float* __restrict__ rel, short* __restrict__ dst)
{
    const int idx = blockIdx.x * 256 + threadIdx.x;   // 256*1024 total
    if (idx < 256 * 1024) {
        const int row = idx >> 10;
        dst[idx] = (row < 129) ? f2bf(rel[idx]) : (short)0;
    }
}

__global__ void hidinit_k(const float* __restrict__ hid,
                          short* __restrict__ h_st, short* __restrict__ h_ed,
                          short* __restrict__ hT_st, short* __restrict__ hT_ed)
{
    const int idx = blockIdx.x * 256 + threadIdx.x;
    if (idx < BL * Dd) {
        const int i = idx >> 10, d = idx & 1023;
        const int b = i >> 9, il = i & 511;
        const short s = f2bf(hid[idx]);
        h_st[idx] = s;
        h_ed[idx] = s;
        hT_st[((size_t)b * Dd + d) * Lr + il] = s;
        hT_ed[((size_t)b * Dd + d) * Lr + il] = s;
    }
}

} // namespace

extern "C" void kernel_launch(void* const* d_in, const int* in_sizes, int n_in,
                              void* d_out, int out_size, void* d_ws, size_t ws_size,
                              hipStream_t stream)
{
    const float* hid  = (const float*)d_in[0];
    const int*   spw  = (const int*)d_in[1];
    const float* Wq[2] = {(const float*)d_in[2], (const float*)d_in[7]};
    const float* bq[2] = {(const float*)d_in[3], (const float*)d_in[8]};
    const float* Wk[2] = {(const float*)d_in[4], (const float*)d_in[9]};
    const float* bk[2] = {(const float*)d_in[5], (const float*)d_in[10]};
    const float* rel[2]= {(const float*)d_in[6], (const float*)d_in[11]};
    const float* combW = (const float*)d_in[12];
    const float* combB = (const float*)d_in[13];

    float* out0 = (float*)d_out;
    float* out1 = out0 + (size_t)BL * Tt * Lr;
    float* out2 = out1 + (size_t)BL * Tt * Lr;

    // ---- workspace layout ----
    short* wsS = (short*)d_ws;
    size_t cur = 0;
    short* hbuf[2][2];
    hbuf[0][0] = wsS + cur; cur += H;
    hbuf[0][1] = wsS + cur; cur += H;
    hbuf[1][0] = wsS + cur; cur += H;
    hbuf[1][1] = wsS + cur; cur += H;
    short* hidT[2];
    hidT[0] = wsS + cur; cur += H;
    hidT[1] = wsS + cur; cur += H;
    short* hc = wsS + cur; cur += 2 * H;
    short* qb = wsS + cur; cur += 2 * H;
    short* kb = wsS + cur; cur += 2 * H;
    short* probs = wsS + cur; cur += 2 * PS;
    short* wqb[2], *wkb[2];
    wqb[0] = wsS + cur; cur += (size_t)Dd * Dd;
    wkb[0] = wsS + cur; cur += (size_t)Dd * Dd;
    wqb[1] = wsS + cur; cur += (size_t)Dd * Dd;
    wkb[1] = wsS + cur; cur += (size_t)Dd * Dd;
    short* combWb = wsS + cur; cur += (size_t)Dd * 2 * Dd;
    short* relp[2];
    relp[0] = wsS + cur; cur += (size_t)256 * Dd;
    relp[1] = wsS + cur; cur += (size_t)256 * Dd;
    float* wsF = (float*)(wsS + cur);
    float* qrelb = wsF;                      // 2 * QS fp32
    float* scb   = wsF + 2 * QS;             // 2 * SC fp32

    // ---- setup conversions ----
    const int DD = Dd * Dd;
    f2bf_k<<<dim3((DD + 255) / 256), 256, 0, stream>>>(Wq[0], wqb[0], DD);
    f2bf_k<<<dim3((DD + 255) / 256), 256, 0, stream>>>(Wk[0], wkb[0], DD);
    f2bf_k<<<dim3((DD + 255) / 256), 256, 0, stream>>>(Wq[1], wqb[1], DD);
    f2bf_k<<<dim3((DD + 255) / 256), 256, 0, stream>>>(Wk[1], wkb[1], DD);
    f2bf_k<<<dim3((2 * DD + 255) / 256), 256, 0, stream>>>(combW, combWb, 2 * DD);
    relpad_k<<<dim3(256 * Dd / 256), 256, 0, stream>>>(rel[0], relp[0]);
    relpad_k<<<dim3(256 * Dd / 256), 256, 0, stream>>>(rel[1], relp[1]);
    hidinit_k<<<dim3((int)(H / 256)), 256, 0, stream>>>(hid, hbuf[0][0], hbuf[1][0],
                                                        hidT[0], hidT[1]);
    masks_k<<<dim3((BL + 255) / 256), 256, 0, stream>>>(spw, out2);

    int curb = 0;
    for (int t = 0; t < Tt; ++t) {
        short* h0 = hbuf[0][curb], *h1 = hbuf[1][curb];
        short* hn0 = hbuf[0][curb ^ 1], *hn1 = hbuf[1][curb ^ 1];
        proj2_k<<<dim3(16, 64), 256, 0, stream>>>(
            h0, h1, wqb[0], wkb[0], wqb[1], wkb[1],
            bq[0], bk[0], bq[1], bk[1], qb, kb);
        qrel2_k<<<dim3(2, 64), 256, 0, stream>>>(qb, relp[0], relp[1], qrelb);
        scores2_k<<<dim3(4, 4, 16), 256, 0, stream>>>(qb, kb, qrelb, scb);
        softmax2_k<<<dim3(Lr, Bb, 2), 256, 0, stream>>>(scb, spw, out0, out1, probs, t);
        pv2_k<<<dim3(8, 4, 16), 256, 0, stream>>>(probs, hidT[0], hidT[1], hc);
        comb2_k<<<dim3(8, 64), 256, 0, stream>>>(h0, h1, hc, combWb, combB,
                                                 hn0, hn1, hidT[0], hidT[1]);
        curb ^= 1;
    }
}